// Round 2
// baseline (818.472 us; speedup 1.0000x reference)
//
#include <hip/hip_runtime.h>
#include <hip/hip_bf16.h>

typedef _Float16 half2v __attribute__((ext_vector_type(2)));
typedef unsigned int u32;

// ---- packed-f16 helpers ------------------------------------------------
__device__ __forceinline__ float dot2(u32 a, u32 b, float c) {
#if __has_builtin(__builtin_amdgcn_fdot2)
  return __builtin_amdgcn_fdot2(__builtin_bit_cast(half2v, a),
                                __builtin_bit_cast(half2v, b), c, false);
#else
  half2v av = __builtin_bit_cast(half2v, a);
  half2v bv = __builtin_bit_cast(half2v, b);
  return c + (float)av.x * (float)bv.x + (float)av.y * (float)bv.y;
#endif
}

__device__ __forceinline__ u32 pack_relu(float a, float b) {
  half2v h;
  h.x = (_Float16)fmaxf(a, 0.0f);
  h.y = (_Float16)fmaxf(b, 0.0f);
  return __builtin_bit_cast(u32, h);
}

__device__ __forceinline__ u32 max2(u32 a, u32 b) {
  half2v x = __builtin_bit_cast(half2v, a);
  half2v y = __builtin_bit_cast(half2v, b);
  x.x = (y.x > x.x) ? y.x : x.x;
  x.y = (y.y > x.y) ? y.y : x.y;
  return __builtin_bit_cast(u32, x);
}

// ---- packed weight layout in d_ws (units of u32 = one half2) -----------
#define W2P 0       // [8][2][25]   co, ci-pair(3->4), ky*5+kx      (400)
#define W3P 400     // [10][4][9]   co, ci-pair(8),    ky*3+kx      (360)
#define W4P 760     // [16][5][9]   co, ci-pair(10),   ky*3+kx      (720)
#define W5P 1480    // [24][8][9]   co, ci-pair(16),   ky*3+kx      (1728)
#define WDP 3208    // [10][108]    o,  (cp*9 + y*3+x) pairs        (1080)
#define WTOT 4288

__global__ void __launch_bounds__(256) prep_weights(
    const float* __restrict__ w2, const float* __restrict__ w3,
    const float* __restrict__ w4, const float* __restrict__ w5,
    const float* __restrict__ wd, u32* __restrict__ wp) {
  int i = threadIdx.x + blockIdx.x * 256;
  if (i < 400) {  // w2p: src [8][3][5][5]
    int co = i / 50, r = i % 50, cp = r / 25, s = r % 25;
    float lo = w2[co * 75 + (2 * cp) * 25 + s];
    float hi = (2 * cp + 1 < 3) ? w2[co * 75 + (2 * cp + 1) * 25 + s] : 0.0f;
    half2v h; h.x = (_Float16)lo; h.y = (_Float16)hi;
    wp[W2P + i] = __builtin_bit_cast(u32, h);
  } else if (i < 760) {  // w3p: src [10][8][3][3]
    int j = i - 400;
    int co = j / 36, r = j % 36, cp = r / 9, s = r % 9;
    half2v h;
    h.x = (_Float16)w3[co * 72 + (2 * cp) * 9 + s];
    h.y = (_Float16)w3[co * 72 + (2 * cp + 1) * 9 + s];
    wp[W3P + j] = __builtin_bit_cast(u32, h);
  } else if (i < 1480) {  // w4p: src [16][10][3][3]
    int j = i - 760;
    int co = j / 45, r = j % 45, cp = r / 9, s = r % 9;
    half2v h;
    h.x = (_Float16)w4[co * 90 + (2 * cp) * 9 + s];
    h.y = (_Float16)w4[co * 90 + (2 * cp + 1) * 9 + s];
    wp[W4P + j] = __builtin_bit_cast(u32, h);
  } else if (i < 3208) {  // w5p: src [24][16][3][3]
    int j = i - 1480;
    int co = j / 72, r = j % 72, cp = r / 9, s = r % 9;
    half2v h;
    h.x = (_Float16)w5[co * 144 + (2 * cp) * 9 + s];
    h.y = (_Float16)w5[co * 144 + (2 * cp + 1) * 9 + s];
    wp[W5P + j] = __builtin_bit_cast(u32, h);
  } else if (i < WTOT) {  // wdp: src [10][216], flatten k = c*9 + y*3 + x
    int j = i - 3208;
    int o = j / 108, r = j % 108, cp = r / 9, s = r % 9;
    half2v h;
    h.x = (_Float16)wd[o * 216 + (2 * cp) * 9 + s];
    h.y = (_Float16)wd[o * 216 + (2 * cp + 1) * 9 + s];
    wp[WDP + j] = __builtin_bit_cast(u32, h);
  }
}

// ---- fused network: 2 images per 256-thread block ----------------------
// LDS arenas per image (u32 units), ping-pong A/B with zeroed halos:
//   A: in_p f32[34][34](1156) -> a2p[4][29][29](3364) -> a3p[5][16][16](1280)
//      -> p2p[8][9][9](648) -> p3[12][3][3](108) + dense partials
//   B: a1p[2][32][32](2048) -> p1p[4][16][16](1024) -> a4p[8][15][15](1800)
//      -> a5p[12][7][7](588)
#define AR_A 3376
#define AR_B 2048
#define AR (AR_A + AR_B)

__global__ void __launch_bounds__(256) mnist_fused(
    const float* __restrict__ in, const float* __restrict__ w1,
    const u32* __restrict__ wp, float* __restrict__ out) {
  __shared__ u32 smem[2 * AR];  // 43392 B
  const int t = threadIdx.x;
  const int u = t & 127;
  const int img = t >> 7;
  const long long b = (long long)blockIdx.x * 2 + img;
  u32* SA = smem + img * AR;
  u32* SB = SA + AR_A;
  float* SAf = (float*)SA;

  // zero in_p (A) and a1p (B)
  for (int i = u; i < 1156; i += 128) SA[i] = 0;
  for (int i = u; i < 2048; i += 128) SB[i] = 0;
  __syncthreads();

  // stage input (fp32, halo 3)
  {
    const float* inb = in + b * 784;
    for (int p = u; p < 784; p += 128) {
      int y = p / 28, x = p % 28;
      SAf[(y + 3) * 34 + (x + 3)] = inb[p];
    }
  }
  __syncthreads();

  // conv1: 7x7, 1->3, fp32, ReLU -> a1p (f16x2, ch pairs (0,1),(2,0))
  for (int p = u; p < 784; p += 128) {
    int y = p / 28, x = p % 28;
    float a0 = 0.f, a1 = 0.f, a2 = 0.f;
    for (int ky = 0; ky < 7; ++ky) {
      const float* row = SAf + (y + ky) * 34 + x;
      #pragma unroll
      for (int kx = 0; kx < 7; ++kx) {
        float v = row[kx];
        int s = ky * 7 + kx;
        a0 += v * w1[s];
        a1 += v * w1[49 + s];
        a2 += v * w1[98 + s];
      }
    }
    int o = (y + 2) * 32 + (x + 2);
    SB[o] = pack_relu(a0, a1);
    SB[1024 + o] = pack_relu(a2, 0.0f);
  }
  __syncthreads();

  // zero a2p
  for (int i = u; i < 3364; i += 128) SA[i] = 0;
  __syncthreads();

  // conv2: 5x5, cin 3(->2 pairs), cout 8 -> a2p (halo 1)
  for (int p = u; p < 784; p += 128) {
    int y = p / 28, x = p % 28;
    float acc[8] = {0.f, 0.f, 0.f, 0.f, 0.f, 0.f, 0.f, 0.f};
    for (int cp = 0; cp < 2; ++cp)
      for (int ky = 0; ky < 5; ++ky) {
        const u32* row = SB + cp * 1024 + (y + ky) * 32 + x;
        const u32* wrow = wp + W2P + cp * 25 + ky * 5;
        #pragma unroll
        for (int kx = 0; kx < 5; ++kx) {
          u32 a = row[kx];
          #pragma unroll
          for (int co = 0; co < 8; ++co)
            acc[co] = dot2(a, wrow[co * 50 + kx], acc[co]);
        }
      }
    int o = (y + 1) * 29 + (x + 1);
    SA[o] = pack_relu(acc[0], acc[1]);
    SA[841 + o] = pack_relu(acc[2], acc[3]);
    SA[1682 + o] = pack_relu(acc[4], acc[5]);
    SA[2523 + o] = pack_relu(acc[6], acc[7]);
  }
  __syncthreads();

  // zero p1p
  for (int i = u; i < 1024; i += 128) SB[i] = 0;
  __syncthreads();

  // pool1 3x3 s2 p1: a2p -> p1p[4][16][16] (halo 1)
  for (int q = u; q < 784; q += 128) {
    int cp = q / 196, r = q % 196, y = r / 14, x = r % 14;
    const u32* basep = SA + cp * 841 + (2 * y) * 29 + 2 * x;
    u32 m = 0;
    #pragma unroll
    for (int j = 0; j < 3; ++j)
      #pragma unroll
      for (int k = 0; k < 3; ++k) m = max2(m, basep[j * 29 + k]);
    SB[cp * 256 + (y + 1) * 16 + (x + 1)] = m;
  }
  __syncthreads();

  // zero a3p
  for (int i = u; i < 1280; i += 128) SA[i] = 0;
  __syncthreads();

  // conv3: 3x3, cin 8(4 pairs), cout 10 -> a3p[5][16][16] (halo 1)
  for (int p = u; p < 196; p += 128) {
    int y = p / 14, x = p % 14;
    float acc[10] = {0.f, 0.f, 0.f, 0.f, 0.f, 0.f, 0.f, 0.f, 0.f, 0.f};
    for (int cp = 0; cp < 4; ++cp)
      for (int ky = 0; ky < 3; ++ky) {
        const u32* row = SB + cp * 256 + (y + ky) * 16 + x;
        const u32* wrow = wp + W3P + cp * 9 + ky * 3;
        #pragma unroll
        for (int kx = 0; kx < 3; ++kx) {
          u32 a = row[kx];
          #pragma unroll
          for (int co = 0; co < 10; ++co)
            acc[co] = dot2(a, wrow[co * 36 + kx], acc[co]);
        }
      }
    int o = (y + 1) * 16 + (x + 1);
    #pragma unroll
    for (int c = 0; c < 5; ++c) SA[c * 256 + o] = pack_relu(acc[2 * c], acc[2 * c + 1]);
  }
  __syncthreads();

  // zero a4p
  for (int i = u; i < 1800; i += 128) SB[i] = 0;
  __syncthreads();

  // conv4: 3x3, cin 10(5 pairs), cout 16 -> a4p[8][15][15] (halo 1)
  for (int p = u; p < 196; p += 128) {
    int y = p / 14, x = p % 14;
    float acc[16] = {0.f, 0.f, 0.f, 0.f, 0.f, 0.f, 0.f, 0.f,
                     0.f, 0.f, 0.f, 0.f, 0.f, 0.f, 0.f, 0.f};
    for (int cp = 0; cp < 5; ++cp)
      for (int ky = 0; ky < 3; ++ky) {
        const u32* row = SA + cp * 256 + (y + ky) * 16 + x;
        const u32* wrow = wp + W4P + cp * 9 + ky * 3;
        #pragma unroll
        for (int kx = 0; kx < 3; ++kx) {
          u32 a = row[kx];
          #pragma unroll
          for (int co = 0; co < 16; ++co)
            acc[co] = dot2(a, wrow[co * 45 + kx], acc[co]);
        }
      }
    int o = (y + 1) * 15 + (x + 1);
    #pragma unroll
    for (int c = 0; c < 8; ++c) SB[c * 225 + o] = pack_relu(acc[2 * c], acc[2 * c + 1]);
  }
  __syncthreads();

  // zero p2p
  for (int i = u; i < 648; i += 128) SA[i] = 0;
  __syncthreads();

  // pool2 3x3 s2 p1: a4p -> p2p[8][9][9] (halo 1)
  for (int q = u; q < 392; q += 128) {
    int cp = q / 49, r = q % 49, y = r / 7, x = r % 7;
    const u32* basep = SB + cp * 225 + (2 * y) * 15 + 2 * x;
    u32 m = 0;
    #pragma unroll
    for (int j = 0; j < 3; ++j)
      #pragma unroll
      for (int k = 0; k < 3; ++k) m = max2(m, basep[j * 15 + k]);
    SA[cp * 81 + (y + 1) * 9 + (x + 1)] = m;
  }
  __syncthreads();

  // conv5: 3x3, cin 16(8 pairs), cout 24 -> a5p[12][7][7]
  // wave-uniform co-groups: waves {0,1} -> co 0..11, waves {2,3} -> co 12..23
  {
    int w = t >> 6, lane = t & 63;
    int cog = w >> 1;
    int unit = ((w & 1) << 6) + lane;  // 0..127
    if (unit < 98) {
      int im = unit / 49, px = unit % 49;
      int y = px / 7, x = px % 7;
      u32* SA2 = smem + im * AR;
      u32* SB2 = SA2 + AR_A;
      float acc[12] = {0.f, 0.f, 0.f, 0.f, 0.f, 0.f, 0.f, 0.f, 0.f, 0.f, 0.f, 0.f};
      for (int cp = 0; cp < 8; ++cp)
        for (int ky = 0; ky < 3; ++ky) {
          const u32* row = SA2 + cp * 81 + (y + ky) * 9 + x;
          const u32* wrow = wp + W5P + (12 * cog) * 72 + cp * 9 + ky * 3;
          #pragma unroll
          for (int kx = 0; kx < 3; ++kx) {
            u32 a = row[kx];
            #pragma unroll
            for (int j = 0; j < 12; ++j)
              acc[j] = dot2(a, wrow[j * 72 + kx], acc[j]);
          }
        }
      int o = y * 7 + x;
      #pragma unroll
      for (int c = 0; c < 6; ++c)
        SB2[(6 * cog + c) * 49 + o] = pack_relu(acc[2 * c], acc[2 * c + 1]);
    }
  }
  __syncthreads();

  // pool3 3x3 s2 p0: a5p -> p3[12][3][3] at SA[0..107]
  for (int q = u; q < 108; q += 128) {
    int cp = q / 9, r = q % 9, y = r / 3, x = r % 3;
    const u32* basep = SB + cp * 49 + (2 * y) * 7 + 2 * x;
    u32 m = 0;
    #pragma unroll
    for (int j = 0; j < 3; ++j)
      #pragma unroll
      for (int k = 0; k < 3; ++k) m = max2(m, basep[j * 7 + k]);
    SA[cp * 9 + r] = m;
  }
  __syncthreads();

  // dense: 2 img x 10 outs x 12 chunks of 9 pairs = 240 units
  if (t < 240) {
    int im = t / 120, r = t % 120, o = r / 12, c = r % 12;
    const u32* p3 = smem + im * AR;
    const u32* wrow = wp + WDP + o * 108 + c * 9;
    float acc = 0.f;
    #pragma unroll
    for (int s = 0; s < 9; ++s) acc = dot2(p3[c * 9 + s], wrow[s], acc);
    ((float*)(smem + im * AR))[128 + o * 12 + c] = acc;
  }
  __syncthreads();
  if (t < 20) {
    int im = t / 10, o = t % 10;
    const float* par = (const float*)(smem + im * AR) + 128 + o * 12;
    float s = 0.f;
    #pragma unroll
    for (int c = 0; c < 12; ++c) s += par[c];
    out[((long long)blockIdx.x * 2 + im) * 10 + o] = s;
  }
}

extern "C" void kernel_launch(void* const* d_in, const int* in_sizes, int n_in,
                              void* d_out, int out_size, void* d_ws, size_t ws_size,
                              hipStream_t stream) {
  const float* in = (const float*)d_in[0];
  const float* w1 = (const float*)d_in[1];
  const float* w2 = (const float*)d_in[2];
  const float* w3 = (const float*)d_in[3];
  const float* w4 = (const float*)d_in[4];
  const float* w5 = (const float*)d_in[5];
  const float* wd = (const float*)d_in[6];
  u32* wp = (u32*)d_ws;
  float* out = (float*)d_out;
  int B = in_sizes[0] / 784;

  prep_weights<<<(WTOT + 255) / 256, 256, 0, stream>>>(w2, w3, w4, w5, wd, wp);
  mnist_fused<<<B / 2, 256, 0, stream>>>(in, w1, wp, out);
}

// Round 5
// 598.479 us; speedup vs baseline: 1.3676x; 1.3676x over previous
//
#include <hip/hip_runtime.h>
#include <hip/hip_bf16.h>

typedef _Float16 half2v __attribute__((ext_vector_type(2)));
typedef unsigned int u32;

// single-instruction packed f16 dot with f32 accumulate
__device__ __forceinline__ float dot2(u32 a, u32 b, float c) {
  float d;
  asm("v_dot2_f32_f16 %0, %1, %2, %3" : "=v"(d) : "v"(a), "v"(b), "v"(c));
  return d;
}

// pack two f32 -> f16x2 (round-toward-zero pack instr), as u32
__device__ __forceinline__ u32 pkrtz(float a, float b) {
  return __builtin_bit_cast(u32, __builtin_amdgcn_cvt_pkrtz(a, b));
}

__device__ __forceinline__ u32 pack_relu(float a, float b) {
  return pkrtz(fmaxf(a, 0.0f), fmaxf(b, 0.0f));
}

__device__ __forceinline__ u32 max2(u32 a, u32 b) {
  half2v x = __builtin_bit_cast(half2v, a);
  half2v y = __builtin_bit_cast(half2v, b);
  x.x = (y.x > x.x) ? y.x : x.x;
  x.y = (y.y > x.y) ? y.y : x.y;
  return __builtin_bit_cast(u32, x);
}

// ---- packed weight layout in d_ws (u32 = one half2 pair) ---------------
// per-layer blocks ordered [cp][ky][kx][co] so each (cp,ky) slice is
// contiguous + 16B aligned for b128 LDS loads.
#define W2P 0       // [2][5][5kx][8co]          = 400
#define W3P 400     // [4][3][32: kx*10+co pad]  = 384
#define W4P 784     // [5][3][3kx][16co]         = 720
#define W5P 1504    // [8][3][3kx][24co]         = 1728
#define WDP 3232    // [10][108]                 = 1080
#define WTOT 4312

__global__ void __launch_bounds__(256) prep_weights(
    const float* __restrict__ w2, const float* __restrict__ w3,
    const float* __restrict__ w4, const float* __restrict__ w5,
    const float* __restrict__ wd, u32* __restrict__ wp) {
  int i = threadIdx.x + blockIdx.x * 256;
  if (i < 400) {  // w2: src [8][3][5][5]
    int co = i & 7, r = i >> 3;
    int kx = r % 5, ky = (r / 5) % 5, cp = r / 25;
    int s = ky * 5 + kx;
    float lo = w2[co * 75 + (2 * cp) * 25 + s];
    float hi = (2 * cp + 1 < 3) ? w2[co * 75 + (2 * cp + 1) * 25 + s] : 0.0f;
    wp[W2P + i] = pkrtz(lo, hi);
  } else if (i < 784) {  // w3: src [10][8][3][3]
    int j = i - 400;
    int b = j >> 5, e = j & 31;
    int cp = b / 3, ky = b % 3;
    u32 v = 0;
    if (e < 30) {
      int kx = e / 10, co = e % 10, s = ky * 3 + kx;
      v = pkrtz(w3[co * 72 + (2 * cp) * 9 + s], w3[co * 72 + (2 * cp + 1) * 9 + s]);
    }
    wp[W3P + j] = v;
  } else if (i < 1504) {  // w4: src [16][10][3][3]
    int j = i - 784;
    int co = j & 15, r = j >> 4;
    int kx = r % 3, ky = (r / 3) % 3, cp = r / 9;
    int s = ky * 3 + kx;
    wp[W4P + j] = pkrtz(w4[co * 90 + (2 * cp) * 9 + s], w4[co * 90 + (2 * cp + 1) * 9 + s]);
  } else if (i < 3232) {  // w5: src [24][16][3][3]
    int j = i - 1504;
    int co = j % 24, r = j / 24;
    int kx = r % 3, ky = (r / 3) % 3, cp = r / 9;
    int s = ky * 3 + kx;
    wp[W5P + j] = pkrtz(w5[co * 144 + (2 * cp) * 9 + s], w5[co * 144 + (2 * cp + 1) * 9 + s]);
  } else if (i < WTOT) {  // wd: src [10][216], k = ci*9 + s
    int j = i - 3232;
    int o = j / 108, r = j % 108, cp = r / 9, s = r % 9;
    wp[WDP + j] = pkrtz(wd[o * 216 + (2 * cp) * 9 + s], wd[o * 216 + (2 * cp + 1) * 9 + s]);
  }
}

// ---- fused network: 2 images per 256-thread block ----------------------
#define AR_A 3376
#define AR_B 2048
#define AR (AR_A + AR_B)
#define WSOFF (2 * AR)  // 1728-u32 per-layer weight scratch (shared)
#define SMEMN (2 * AR + 1728)  // 12576 u32 = 50304 B -> 3 blocks/CU

__global__ void __launch_bounds__(256) mnist_fused(
    const float* __restrict__ in, const float* __restrict__ w1,
    const u32* __restrict__ wp, float* __restrict__ out) {
  __shared__ u32 smem[SMEMN];
  const int t = threadIdx.x;
  const int u = t & 127;
  const int img = t >> 7;
  const long long b = (long long)blockIdx.x * 2 + img;
  u32* SA = smem + img * AR;
  u32* SB = SA + AR_A;
  float* SAf = (float*)SA;
  u32* WS = smem + WSOFF;
  float* WSf = (float*)WS;

  // phase 0: zero in_p + a1p, stage w1 (147 f32) into scratch
  for (int i = u; i < 1156; i += 128) SA[i] = 0;
  for (int i = u; i < 2048; i += 128) SB[i] = 0;
  for (int i = t; i < 147; i += 256) WSf[i] = w1[i];
  __syncthreads();

  // stage input (fp32, halo 3)
  {
    const float* inb = in + b * 784;
    for (int p = u; p < 784; p += 128) {
      int y = p / 28, x = p % 28;
      SAf[(y + 3) * 34 + (x + 3)] = inb[p];
    }
  }
  __syncthreads();

  // conv1: 7x7, 1->3, fp32 -> a1p (f16x2 pairs (0,1),(2,-))
  {
    float acc[7][3] = {};
    int yy[7], xx[7];
    #pragma unroll
    for (int i = 0; i < 7; ++i) { int p = u + 128 * i; yy[i] = p / 28; xx[i] = p % 28; }
    #pragma unroll 1
    for (int ky = 0; ky < 7; ++ky) {
      float wk[21];
      #pragma unroll
      for (int co = 0; co < 3; ++co)
        #pragma unroll
        for (int kx = 0; kx < 7; ++kx) wk[co * 7 + kx] = WSf[co * 49 + ky * 7 + kx];
      #pragma unroll
      for (int i = 0; i < 7; ++i) {
        int p = u + 128 * i;
        if (p < 784) {
          const float* row = SAf + (yy[i] + ky) * 34 + xx[i];
          float r[7];
          #pragma unroll
          for (int kx = 0; kx < 7; ++kx) r[kx] = row[kx];
          #pragma unroll
          for (int co = 0; co < 3; ++co)
            #pragma unroll
            for (int kx = 0; kx < 7; ++kx)
              acc[i][co] = fmaf(r[kx], wk[co * 7 + kx], acc[i][co]);
        }
      }
    }
    #pragma unroll
    for (int i = 0; i < 7; ++i) {
      int p = u + 128 * i;
      if (p < 784) {
        int o = (yy[i] + 2) * 32 + xx[i] + 2;
        SB[o] = pack_relu(acc[i][0], acc[i][1]);
        SB[1024 + o] = pack_relu(acc[i][2], 0.0f);
      }
    }
  }
  __syncthreads();

  // zero a2p; stage w2 (400)
  for (int i = u; i < 3364; i += 128) SA[i] = 0;
  for (int i = t; i < 400; i += 256) WS[i] = wp[W2P + i];
  __syncthreads();

  // conv2: 5x5, cin 3(2 pairs), cout 8 -> a2p[4][29][29]
  #pragma unroll 1
  for (int pass = 0; pass < 2; ++pass) {
    int pb = pass * 512;
    float acc[4][8] = {};
    int yy[4], xx[4];
    #pragma unroll
    for (int i = 0; i < 4; ++i) { int p = u + pb + 128 * i; yy[i] = p / 28; xx[i] = p % 28; }
    #pragma unroll 1
    for (int cp = 0; cp < 2; ++cp)
      #pragma unroll 1
      for (int ky = 0; ky < 5; ++ky) {
        u32 w[40];
        int blk = (cp * 5 + ky) * 40;
        #pragma unroll
        for (int q = 0; q < 40; ++q) w[q] = WS[blk + q];
        #pragma unroll
        for (int i = 0; i < 4; ++i) {
          int p = u + pb + 128 * i;
          if (p < 784) {
            const u32* row = SB + cp * 1024 + (yy[i] + ky) * 32 + xx[i];
            u32 a[5];
            #pragma unroll
            for (int kx = 0; kx < 5; ++kx) a[kx] = row[kx];
            #pragma unroll
            for (int kx = 0; kx < 5; ++kx)
              #pragma unroll
              for (int co = 0; co < 8; ++co)
                acc[i][co] = dot2(a[kx], w[kx * 8 + co], acc[i][co]);
          }
        }
      }
    #pragma unroll
    for (int i = 0; i < 4; ++i) {
      int p = u + pb + 128 * i;
      if (p < 784) {
        int o = (yy[i] + 1) * 29 + xx[i] + 1;
        SA[o] = pack_relu(acc[i][0], acc[i][1]);
        SA[841 + o] = pack_relu(acc[i][2], acc[i][3]);
        SA[1682 + o] = pack_relu(acc[i][4], acc[i][5]);
        SA[2523 + o] = pack_relu(acc[i][6], acc[i][7]);
      }
    }
  }
  __syncthreads();

  // zero p1p; stage w3 (384)
  for (int i = u; i < 1024; i += 128) SB[i] = 0;
  for (int i = t; i < 384; i += 256) WS[i] = wp[W3P + i];
  __syncthreads();

  // pool1 3x3 s2 p1: a2p -> p1p[4][16][16]
  for (int q = u; q < 784; q += 128) {
    int cp = q / 196, r = q % 196, y = r / 14, x = r % 14;
    const u32* basep = SA + cp * 841 + (2 * y) * 29 + 2 * x;
    u32 m = 0;
    #pragma unroll
    for (int j = 0; j < 3; ++j)
      #pragma unroll
      for (int k = 0; k < 3; ++k) m = max2(m, basep[j * 29 + k]);
    SB[cp * 256 + (y + 1) * 16 + (x + 1)] = m;
  }
  __syncthreads();

  // zero a3p
  for (int i = u; i < 1280; i += 128) SA[i] = 0;
  __syncthreads();

  // conv3: 3x3, cin 8(4 pairs), cout 10 -> a3p[5][16][16]
  {
    float acc[2][10] = {};
    int yy[2], xx[2];
    #pragma unroll
    for (int i = 0; i < 2; ++i) { int p = u + 128 * i; yy[i] = p / 14; xx[i] = p % 14; }
    #pragma unroll 1
    for (int cp = 0; cp < 4; ++cp)
      #pragma unroll 1
      for (int ky = 0; ky < 3; ++ky) {
        u32 w[32];
        int blk = (cp * 3 + ky) * 32;
        #pragma unroll
        for (int q = 0; q < 32; ++q) w[q] = WS[blk + q];
        #pragma unroll
        for (int i = 0; i < 2; ++i) {
          int p = u + 128 * i;
          if (p < 196) {
            const u32* row = SB + cp * 256 + (yy[i] + ky) * 16 + xx[i];
            u32 a[3];
            #pragma unroll
            for (int kx = 0; kx < 3; ++kx) a[kx] = row[kx];
            #pragma unroll
            for (int kx = 0; kx < 3; ++kx)
              #pragma unroll
              for (int co = 0; co < 10; ++co)
                acc[i][co] = dot2(a[kx], w[kx * 10 + co], acc[i][co]);
          }
        }
      }
    #pragma unroll
    for (int i = 0; i < 2; ++i) {
      int p = u + 128 * i;
      if (p < 196) {
        int o = (yy[i] + 1) * 16 + xx[i] + 1;
        #pragma unroll
        for (int c = 0; c < 5; ++c) SA[c * 256 + o] = pack_relu(acc[i][2 * c], acc[i][2 * c + 1]);
      }
    }
  }
  __syncthreads();

  // zero a4p; stage w4 (720)
  for (int i = u; i < 1800; i += 128) SB[i] = 0;
  for (int i = t; i < 720; i += 256) WS[i] = wp[W4P + i];
  __syncthreads();

  // conv4: 3x3, cin 10(5 pairs), cout 16 -> a4p[8][15][15]
  {
    float acc[2][16] = {};
    int yy[2], xx[2];
    #pragma unroll
    for (int i = 0; i < 2; ++i) { int p = u + 128 * i; yy[i] = p / 14; xx[i] = p % 14; }
    #pragma unroll 1
    for (int cp = 0; cp < 5; ++cp)
      #pragma unroll 1
      for (int ky = 0; ky < 3; ++ky) {
        u32 w[48];
        int blk = (cp * 3 + ky) * 48;
        #pragma unroll
        for (int q = 0; q < 48; ++q) w[q] = WS[blk + q];
        #pragma unroll
        for (int i = 0; i < 2; ++i) {
          int p = u + 128 * i;
          if (p < 196) {
            const u32* row = SA + cp * 256 + (yy[i] + ky) * 16 + xx[i];
            u32 a[3];
            #pragma unroll
            for (int kx = 0; kx < 3; ++kx) a[kx] = row[kx];
            #pragma unroll
            for (int kx = 0; kx < 3; ++kx)
              #pragma unroll
              for (int co = 0; co < 16; ++co)
                acc[i][co] = dot2(a[kx], w[kx * 16 + co], acc[i][co]);
          }
        }
      }
    #pragma unroll
    for (int i = 0; i < 2; ++i) {
      int p = u + 128 * i;
      if (p < 196) {
        int o = (yy[i] + 1) * 15 + xx[i] + 1;
        #pragma unroll
        for (int c = 0; c < 8; ++c) SB[c * 225 + o] = pack_relu(acc[i][2 * c], acc[i][2 * c + 1]);
      }
    }
  }
  __syncthreads();

  // zero p2p; stage w5 (1728)
  for (int i = u; i < 648; i += 128) SA[i] = 0;
  for (int i = t; i < 1728; i += 256) WS[i] = wp[W5P + i];
  __syncthreads();

  // pool2 3x3 s2 p1: a4p -> p2p[8][9][9]
  for (int q = u; q < 392; q += 128) {
    int cp = q / 49, r = q % 49, y = r / 7, x = r % 7;
    const u32* basep = SB + cp * 225 + (2 * y) * 15 + 2 * x;
    u32 m = 0;
    #pragma unroll
    for (int j = 0; j < 3; ++j)
      #pragma unroll
      for (int k = 0; k < 3; ++k) m = max2(m, basep[j * 15 + k]);
    SA[cp * 81 + (y + 1) * 9 + (x + 1)] = m;
  }
  __syncthreads();

  // conv5: 3x3, cin 16(8 pairs), cout 24 -> a5p[12][7][7]
  {
    int w = t >> 6, lane = t & 63;
    int cog = w >> 1;                  // waves {0,1}: co 0..11, {2,3}: co 12..23
    int unit = ((w & 1) << 6) + lane;  // 0..127
    int valid = unit < 98;
    int im = valid ? unit / 49 : 0;
    int pxu = unit % 49;
    int y = pxu / 7, x = pxu % 7;
    u32* SA2 = smem + im * AR;
    u32* SB2 = SA2 + AR_A;
    float acc[12] = {};
    #pragma unroll 1
    for (int cp = 0; cp < 8; ++cp)
      #pragma unroll 1
      for (int ky = 0; ky < 3; ++ky) {
        u32 wv[36];
        int base = (cp * 3 + ky) * 72 + cog * 12;
        #pragma unroll
        for (int kx = 0; kx < 3; ++kx)
          #pragma unroll
          for (int j = 0; j < 12; ++j) wv[kx * 12 + j] = WS[base + kx * 24 + j];
        if (valid) {
          const u32* row = SA2 + cp * 81 + (y + ky) * 9 + x;
          u32 a[3];
          #pragma unroll
          for (int kx = 0; kx < 3; ++kx) a[kx] = row[kx];
          #pragma unroll
          for (int kx = 0; kx < 3; ++kx)
            #pragma unroll
            for (int j = 0; j < 12; ++j)
              acc[j] = dot2(a[kx], wv[kx * 12 + j], acc[j]);
        }
      }
    if (valid) {
      int o = y * 7 + x;
      #pragma unroll
      for (int c = 0; c < 6; ++c)
        SB2[(6 * cog + c) * 49 + o] = pack_relu(acc[2 * c], acc[2 * c + 1]);
    }
  }
  __syncthreads();

  // stage wd (1080); pool3 3x3 s2 p0: a5p -> p3[12][3][3] at SA[0..107]
  for (int i = t; i < 1080; i += 256) WS[i] = wp[WDP + i];
  for (int q = u; q < 108; q += 128) {
    int cp = q / 9, r = q % 9, y = r / 3, x = r % 3;
    const u32* basep = SB + cp * 49 + (2 * y) * 7 + 2 * x;
    u32 m = 0;
    #pragma unroll
    for (int j = 0; j < 3; ++j)
      #pragma unroll
      for (int k = 0; k < 3; ++k) m = max2(m, basep[j * 7 + k]);
    SA[cp * 9 + r] = m;
  }
  __syncthreads();

  // dense: 2 img x 10 outs x 12 chunks of 9 pairs
  if (t < 240) {
    int im = t / 120, r = t % 120, o = r / 12, c = r % 12;
    const u32* p3 = smem + im * AR;
    const u32* wrow = WS + o * 108 + c * 9;
    float acc = 0.f;
    #pragma unroll
    for (int s = 0; s < 9; ++s) acc = dot2(p3[c * 9 + s], wrow[s], acc);
    ((float*)(smem + im * AR))[128 + o * 12 + c] = acc;
  }
  __syncthreads();
  if (t < 20) {
    int im = t / 10, o = t % 10;
    const float* par = (const float*)(smem + im * AR) + 128 + o * 12;
    float s = 0.f;
    #pragma unroll
    for (int c = 0; c < 12; ++c) s += par[c];
    out[((long long)blockIdx.x * 2 + im) * 10 + o] = s;
  }
}

extern "C" void kernel_launch(void* const* d_in, const int* in_sizes, int n_in,
                              void* d_out, int out_size, void* d_ws, size_t ws_size,
                              hipStream_t stream) {
  const float* in = (const float*)d_in[0];
  const float* w1 = (const float*)d_in[1];
  const float* w2 = (const float*)d_in[2];
  const float* w3 = (const float*)d_in[3];
  const float* w4 = (const float*)d_in[4];
  const float* w5 = (const float*)d_in[5];
  const float* wd = (const float*)d_in[6];
  u32* wp = (u32*)d_ws;
  float* out = (float*)d_out;
  int B = in_sizes[0] / 784;

  prep_weights<<<(WTOT + 255) / 256, 256, 0, stream>>>(w2, w3, w4, w5, wd, wp);
  mnist_fused<<<B / 2, 256, 0, stream>>>(in, w1, wp, out);
}